// Round 3
// baseline (424.482 us; speedup 1.0000x reference)
//
#include <hip/hip_runtime.h>
#include <stdint.h>

#define B_ 16
#define C_ 512
#define N_ 4096

typedef float f32x4 __attribute__((ext_vector_type(4)));
typedef __bf16 bf16x8 __attribute__((ext_vector_type(8)));

// fp32 -> bf16 round-to-nearest-even (inputs are finite normals; no NaN path needed)
static __device__ __forceinline__ unsigned short f2bf(float f) {
    unsigned int u = __float_as_uint(f);
    u += 0x7fffu + ((u >> 16) & 1u);
    return (unsigned short)(u >> 16);
}

// async global->LDS, 16B per lane (global_load_lds_dwordx4)
static __device__ __forceinline__ void gload_lds16(const void* g, void* l) {
    __builtin_amdgcn_global_load_lds(
        (__attribute__((address_space(1))) unsigned int*)(g),
        (__attribute__((address_space(3))) unsigned int*)(l),
        16, 0, 0);
}

// Stage one 128x32 A-tile + 128x32 B-tile (4 loads/wave => vmcnt +4).
static __device__ __forceinline__ void stage_pair(const char* Ab, const char* Bb,
                                                  char* as, char* bs, int tid,
                                                  int rowBytes, int m0, int n0, int kByte) {
#pragma unroll
    for (int i = 0; i < 2; ++i) {
        int o = (i * 256 + tid) * 16;            // LDS byte offset, 0..8191
        int mrow = o >> 6, inrow = o & 63;       // 64 B per 32-elem bf16 row
        gload_lds16(Ab + (size_t)(m0 + mrow) * rowBytes + kByte + inrow, as + o);
        gload_lds16(Bb + (size_t)(n0 + mrow) * rowBytes + kByte + inrow, bs + o);
    }
}

// Stage one 128x32 B-tile only (2 loads/wave => vmcnt +2).
static __device__ __forceinline__ void stage_B(const char* Bb, char* bs, int tid,
                                               int rowBytes, int n0, int kByte) {
#pragma unroll
    for (int i = 0; i < 2; ++i) {
        int o = (i * 256 + tid) * 16;
        int nrow = o >> 6, inrow = o & 63;
        gload_lds16(Bb + (size_t)(n0 + nrow) * rowBytes + kByte + inrow, bs + o);
    }
}

// ---------------------------------------------------------------------------
// Kernel 1: x (fp32, BxCxN) -> q16 (bf16, BxCxN) and qt16 (bf16, BxNxC)
// Register 4x4 micro-tile transpose: no LDS, no barriers.
// ---------------------------------------------------------------------------
__global__ __launch_bounds__(256)
void convert_transpose(const float* __restrict__ x,
                       unsigned short* __restrict__ q16,
                       unsigned short* __restrict__ qt16) {
    int b = blockIdx.z;
    int t = threadIdx.x;
    int c0 = blockIdx.y * 64 + (t >> 4) * 4;
    int n0 = blockIdx.x * 64 + (t & 15) * 4;

    const float* xb = x + ((size_t)b * C_ + c0) * N_ + n0;
    unsigned short h[4][4];
#pragma unroll
    for (int i = 0; i < 4; ++i) {
        float4 v = *(const float4*)(xb + (size_t)i * N_);
        h[i][0] = f2bf(v.x); h[i][1] = f2bf(v.y);
        h[i][2] = f2bf(v.z); h[i][3] = f2bf(v.w);
    }
    unsigned short* qb = q16 + ((size_t)b * C_ + c0) * N_ + n0;
#pragma unroll
    for (int i = 0; i < 4; ++i) {
        ushort4 p; p.x = h[i][0]; p.y = h[i][1]; p.z = h[i][2]; p.w = h[i][3];
        *(ushort4*)(qb + (size_t)i * N_) = p;
    }
    unsigned short* qtb = qt16 + ((size_t)b * N_ + n0) * C_ + c0;
#pragma unroll
    for (int j = 0; j < 4; ++j) {
        ushort4 p; p.x = h[0][j]; p.y = h[1][j]; p.z = h[2][j]; p.w = h[3][j];
        *(ushort4*)(qtb + (size_t)j * C_) = p;
    }
}

// ---------------------------------------------------------------------------
// Kernel 2: energy partials, split-K x2, full 4x4 tile grid.
//   e{0,1}[b] (f32 512x512) = Q[b][:, ks*2048:+2048] . (same)^T
// Depth-3 counted-vmcnt pipeline: 4 LDS buffers, stage tile t+3, steady
// vmcnt(8). 512 blocks (2/CU), XCD-swizzled.
// ---------------------------------------------------------------------------
__global__ __launch_bounds__(256)
void gemm_energy(const unsigned short* __restrict__ q16,
                 float* __restrict__ e0, float* __restrict__ e1) {
    // XCD-aware swizzle: 512 = 8 * 64
    int p = (blockIdx.z * 2 + blockIdx.y) * 16 + blockIdx.x;
    int l = (p & 7) * 64 + (p >> 3);
    int tile = l & 15, ks = (l >> 4) & 1, b = l >> 5;
    int m0 = (tile >> 2) * 128, n0 = (tile & 3) * 128;
    int kbeg = ks * 2048;
    const int NT = 64;                       // 2048 / 32

    const char* Ab = (const char*)(q16 + (size_t)b * C_ * N_);
    const int rowB = N_ * 2;

    __shared__ unsigned short As[4][128 * 32];
    __shared__ unsigned short Bs[4][128 * 32];

    int t = threadIdx.x;
    int lane = t & 63, wave = t >> 6;
    int wm = (wave >> 1) * 64, wn = (wave & 1) * 64;
    int qd = lane >> 4, r = lane & 15;

    f32x4 acc[4][4] = {};

    stage_pair(Ab, Ab, (char*)As[0], (char*)Bs[0], t, rowB, m0, n0, (kbeg +  0) * 2);
    stage_pair(Ab, Ab, (char*)As[1], (char*)Bs[1], t, rowB, m0, n0, (kbeg + 32) * 2);
    stage_pair(Ab, Ab, (char*)As[2], (char*)Bs[2], t, rowB, m0, n0, (kbeg + 64) * 2);

    for (int tt = 0; tt < NT; ++tt) {
        if (tt < NT - 2)       asm volatile("s_waitcnt vmcnt(8) lgkmcnt(0)" ::: "memory");
        else if (tt == NT - 2) asm volatile("s_waitcnt vmcnt(4) lgkmcnt(0)" ::: "memory");
        else                   asm volatile("s_waitcnt vmcnt(0) lgkmcnt(0)" ::: "memory");
        __builtin_amdgcn_s_barrier();

        if (tt + 3 < NT) {
            int nb = (tt + 3) & 3;
            stage_pair(Ab, Ab, (char*)As[nb], (char*)Bs[nb], t, rowB,
                       m0, n0, (kbeg + (tt + 3) * 32) * 2);
        }

        const unsigned short* as = As[tt & 3];
        const unsigned short* bs = Bs[tt & 3];
        bf16x8 af[4], bfr[4];
#pragma unroll
        for (int i = 0; i < 4; ++i)
            af[i] = *(const bf16x8*)&as[(wm + i * 16 + r) * 32 + qd * 8];
#pragma unroll
        for (int j = 0; j < 4; ++j)
            bfr[j] = *(const bf16x8*)&bs[(wn + j * 16 + r) * 32 + qd * 8];

        __builtin_amdgcn_s_setprio(1);
#pragma unroll
        for (int i = 0; i < 4; ++i)
#pragma unroll
            for (int j = 0; j < 4; ++j)
                acc[i][j] = __builtin_amdgcn_mfma_f32_16x16x32_bf16(af[i], bfr[j], acc[i][j], 0, 0, 0);
        __builtin_amdgcn_s_setprio(0);
    }

    float* Db = (ks ? e1 : e0) + (size_t)b * C_ * C_;
#pragma unroll
    for (int i = 0; i < 4; ++i)
#pragma unroll
        for (int j = 0; j < 4; ++j) {
            int row = m0 + wm + i * 16 + qd * 4;
            int col = n0 + wn + j * 16 + r;
#pragma unroll
            for (int rr = 0; rr < 4; ++rr)
                Db[(size_t)(row + rr) * C_ + col] = acc[i][j][rr];
        }
}

// ---------------------------------------------------------------------------
// Kernel 3: attention = softmax(-energy) row-wise, summing the two split-K
// partials inline. One block per (b,c) row; output bf16.
// ---------------------------------------------------------------------------
__global__ __launch_bounds__(256)
void softmax_neg(const float* __restrict__ e0, const float* __restrict__ e1,
                 unsigned short* __restrict__ att) {
    size_t row = blockIdx.x;
    const float* a = e0 + row * C_;
    const float* c = e1 + row * C_;
    int t = threadIdx.x;

    float x0 = a[t] + c[t], x1 = a[t + 256] + c[t + 256];
    float m = fminf(x0, x1);                 // min(e) == -max(-e)
#pragma unroll
    for (int off = 32; off > 0; off >>= 1) m = fminf(m, __shfl_down(m, off, 64));
    __shared__ float red[8];
    if ((t & 63) == 0) red[t >> 6] = m;
    __syncthreads();
    m = fminf(fminf(red[0], red[1]), fminf(red[2], red[3]));

    float p0 = __expf(m - x0), p1 = __expf(m - x1);
    float s = p0 + p1;
#pragma unroll
    for (int off = 32; off > 0; off >>= 1) s += __shfl_down(s, off, 64);
    if ((t & 63) == 0) red[4 + (t >> 6)] = s;
    __syncthreads();
    s = red[4] + red[5] + red[6] + red[7];
    float inv = 1.0f / s;

    att[row * C_ + t]       = f2bf(p0 * inv);
    att[row * C_ + t + 256] = f2bf(p1 * inv);
}

// ---------------------------------------------------------------------------
// Kernel 4: y[b] = gamma * (attention[b] . Q[b]) + x[b]
// A (att, 512KB/batch) is L2-resident -> loaded DIRECT to registers, double-
// buffered (afA/afB, 1-iter lookahead). B (qt16) streams through a depth-4
// B-only LDS pipeline (5 x 8KB buffers). Steady-state wait vmcnt(6):
//   per iter issues: stage_B(t+4)=2 + A-loads(t+1)=4; the 6 newest may fly,
//   everything through A(t)/B(t) has landed. 40KB LDS + ~150 VGPR -> 3 blk/CU.
// ---------------------------------------------------------------------------
__global__ __launch_bounds__(256)
void gemm_bt_out(const unsigned short* __restrict__ att,
                 const unsigned short* __restrict__ qt16,
                 const float* __restrict__ x,
                 const float* __restrict__ gamma,
                 float* __restrict__ y) {
    const int K = 512;
    const int NT = K / 32;   // 16
    // linearize + XCD swizzle (2048 = 8 * 256)
    int p = (blockIdx.z * 4 + blockIdx.y) * 32 + blockIdx.x;
    int l = (p & 7) * 256 + (p >> 3);
    int bx = l & 31, by = (l >> 5) & 3, b = l >> 7;

    const char* Ab = (const char*)(att  + (size_t)b * C_ * K);
    const char* Bb = (const char*)(qt16 + (size_t)b * N_ * K);
    int m0 = by * 128;    // c
    int n0 = bx * 128;    // n (spatial)

    __shared__ unsigned short Bs[5][128 * 32];   // 40 KB total

    int t = threadIdx.x;
    int lane = t & 63, wave = t >> 6;
    int wm = (wave >> 1) * 64, wn = (wave & 1) * 64;
    int qd = lane >> 4, r = lane & 15;

    const int rowB = K * 2;   // 1024 B per qt16/att row
    // per-i A row base (includes lane offsets); k-offset added per iter
    const char* Arow[4];
#pragma unroll
    for (int i = 0; i < 4; ++i)
        Arow[i] = Ab + (size_t)(m0 + wm + i * 16 + r) * rowB + qd * 16;

    f32x4 acc[4][4] = {};
    bf16x8 afA[4], afB[4];

    // prologue: A(0) direct loads + B tiles 0..3 staged
#pragma unroll
    for (int i = 0; i < 4; ++i) afA[i] = *(const bf16x8*)(Arow[i]);
    stage_B(Bb, (char*)Bs[0], t, rowB, n0, 0);
    stage_B(Bb, (char*)Bs[1], t, rowB, n0, 64);
    stage_B(Bb, (char*)Bs[2], t, rowB, n0, 128);
    stage_B(Bb, (char*)Bs[3], t, rowB, n0, 192);

#define OUT_ITER(tt, CUR, NXT)                                                  \
    {                                                                           \
        asm volatile("s_waitcnt lgkmcnt(0)" ::: "memory");                      \
        __builtin_amdgcn_s_barrier();                                           \
        if ((tt) + 4 < NT)                                                      \
            stage_B(Bb, (char*)Bs[((tt) + 4) % 5], t, rowB, n0, ((tt) + 4) * 64); \
        if ((tt) + 1 < NT) {                                                    \
            _Pragma("unroll")                                                   \
            for (int i = 0; i < 4; ++i)                                         \
                NXT[i] = *(const bf16x8*)(Arow[i] + ((tt) + 1) * 64);           \
        }                                                                       \
        if ((tt) + 4 < NT)       asm volatile("s_waitcnt vmcnt(6)" ::: "memory"); \
        else if ((tt) + 1 < NT)  asm volatile("s_waitcnt vmcnt(4)" ::: "memory"); \
        else                     asm volatile("s_waitcnt vmcnt(0)" ::: "memory"); \
        const unsigned short* bs = Bs[(tt) % 5];                                \
        bf16x8 bfr[4];                                                          \
        _Pragma("unroll")                                                       \
        for (int j = 0; j < 4; ++j)                                             \
            bfr[j] = *(const bf16x8*)&bs[(wn + j * 16 + r) * 32 + qd * 8];      \
        __builtin_amdgcn_s_setprio(1);                                          \
        _Pragma("unroll")                                                       \
        for (int i = 0; i < 4; ++i)                                             \
            _Pragma("unroll")                                                   \
            for (int j = 0; j < 4; ++j)                                         \
                acc[i][j] = __builtin_amdgcn_mfma_f32_16x16x32_bf16(CUR[i], bfr[j], acc[i][j], 0, 0, 0); \
        __builtin_amdgcn_s_setprio(0);                                          \
    }

#pragma unroll
    for (int t2 = 0; t2 < NT / 2; ++t2) {
        OUT_ITER(2 * t2,     afA, afB);
        OUT_ITER(2 * t2 + 1, afB, afA);
    }
#undef OUT_ITER

    float g = gamma[0];
    const float* xb = x + (size_t)b * C_ * N_;
    float*       yb = y + (size_t)b * C_ * N_;
#pragma unroll
    for (int i = 0; i < 4; ++i)
#pragma unroll
        for (int j = 0; j < 4; ++j) {
            int row = m0 + wm + i * 16 + qd * 4;
            int col = n0 + wn + j * 16 + r;
#pragma unroll
            for (int rr = 0; rr < 4; ++rr) {
                size_t idx = (size_t)(row + rr) * N_ + col;
                yb[idx] = g * acc[i][j][rr] + xb[idx];
            }
        }
}

// ---------------------------------------------------------------------------
// Workspace layout (bytes):
//   q16   @ 0          : 67,108,864
//   qt16  @ 67108864   : 67,108,864
//   att16 @ 134217728  :  8,388,608
//   e0    @ 142606336  : 16,777,216      -> total 159,383,552
//   e1 = d_out (scratch; fully overwritten by gemm_bt_out afterwards)
// ---------------------------------------------------------------------------
extern "C" void kernel_launch(void* const* d_in, const int* in_sizes, int n_in,
                              void* d_out, int out_size, void* d_ws, size_t ws_size,
                              hipStream_t stream) {
    const float* x     = (const float*)d_in[0];
    const float* gamma = (const float*)d_in[1];
    float*       y     = (float*)d_out;

    char* ws = (char*)d_ws;
    unsigned short* q16   = (unsigned short*)(ws);
    unsigned short* qt16  = (unsigned short*)(ws + 67108864);
    unsigned short* att16 = (unsigned short*)(ws + 134217728);
    float*          e0    = (float*)(ws + 142606336);
    float*          e1    = (float*)d_out;   // scratch until gemm_bt_out runs

    convert_transpose<<<dim3(N_ / 64, C_ / 64, B_), dim3(256), 0, stream>>>(x, q16, qt16);
    gemm_energy<<<dim3(16, 2, B_), dim3(256), 0, stream>>>(q16, e0, e1);
    softmax_neg<<<dim3(B_ * C_), dim3(256), 0, stream>>>(e0, e1, att16);
    gemm_bt_out<<<dim3(N_ / 128, C_ / 128, B_), dim3(256), 0, stream>>>(att16, qt16, x, gamma, y);
}

// Round 4
// 390.645 us; speedup vs baseline: 1.0866x; 1.0866x over previous
//
#include <hip/hip_runtime.h>
#include <stdint.h>

#define B_ 16
#define C_ 512
#define N_ 4096

typedef float f32x4 __attribute__((ext_vector_type(4)));
typedef __bf16 bf16x8 __attribute__((ext_vector_type(8)));

// fp32 -> bf16 round-to-nearest-even (inputs are finite normals; no NaN path needed)
static __device__ __forceinline__ unsigned short f2bf(float f) {
    unsigned int u = __float_as_uint(f);
    u += 0x7fffu + ((u >> 16) & 1u);
    return (unsigned short)(u >> 16);
}

// async global->LDS, 16B per lane (global_load_lds_dwordx4)
static __device__ __forceinline__ void gload_lds16(const void* g, void* l) {
    __builtin_amdgcn_global_load_lds(
        (__attribute__((address_space(1))) unsigned int*)(g),
        (__attribute__((address_space(3))) unsigned int*)(l),
        16, 0, 0);
}

// Stage one 256x32 A-tile + 256x32 B-tile into LDS with 512 threads.
// 4 global_load_lds_dwordx4 per thread per call => vmcnt +4 per wave.
static __device__ __forceinline__ void stage_pair512(const char* Ab, const char* Bb,
                                                     char* as, char* bs, int tid,
                                                     int rowBytes, int m0, int n0, int kByte) {
#pragma unroll
    for (int i = 0; i < 2; ++i) {
        int o = (i * 512 + tid) * 16;            // LDS byte offset, 0..16383
        int mrow = o >> 6, inrow = o & 63;       // 64 B per 32-elem bf16 row
        gload_lds16(Ab + (size_t)(m0 + mrow) * rowBytes + kByte + inrow, as + o);
        gload_lds16(Bb + (size_t)(n0 + mrow) * rowBytes + kByte + inrow, bs + o);
    }
}

// ---------------------------------------------------------------------------
// Kernel 1: x (fp32, BxCxN) -> q16 (bf16, BxCxN) and qt16 (bf16, BxNxC)
// Register 4x4 micro-tile transpose: no LDS, no barriers.
// ---------------------------------------------------------------------------
__global__ __launch_bounds__(256)
void convert_transpose(const float* __restrict__ x,
                       unsigned short* __restrict__ q16,
                       unsigned short* __restrict__ qt16) {
    int b = blockIdx.z;
    int t = threadIdx.x;
    int c0 = blockIdx.y * 64 + (t >> 4) * 4;
    int n0 = blockIdx.x * 64 + (t & 15) * 4;

    const float* xb = x + ((size_t)b * C_ + c0) * N_ + n0;
    unsigned short h[4][4];
#pragma unroll
    for (int i = 0; i < 4; ++i) {
        float4 v = *(const float4*)(xb + (size_t)i * N_);
        h[i][0] = f2bf(v.x); h[i][1] = f2bf(v.y);
        h[i][2] = f2bf(v.z); h[i][3] = f2bf(v.w);
    }
    unsigned short* qb = q16 + ((size_t)b * C_ + c0) * N_ + n0;
#pragma unroll
    for (int i = 0; i < 4; ++i) {
        ushort4 p; p.x = h[i][0]; p.y = h[i][1]; p.z = h[i][2]; p.w = h[i][3];
        *(ushort4*)(qb + (size_t)i * N_) = p;
    }
    unsigned short* qtb = qt16 + ((size_t)b * N_ + n0) * C_ + c0;
#pragma unroll
    for (int j = 0; j < 4; ++j) {
        ushort4 p; p.x = h[0][j]; p.y = h[1][j]; p.z = h[2][j]; p.w = h[3][j];
        *(ushort4*)(qtb + (size_t)j * C_) = p;
    }
}

// ---------------------------------------------------------------------------
// Kernel 2: energy partials, split-K x4, 256x256 tiles, 8 waves (512 thr).
//   part[ks][b] (f32 512x512 quadrant) = Q[b][:, ks*1024:+1024] . (same)^T
// Depth-2 counted-vmcnt loop (r1-proven, scaled): 3 x 32KB LDS buffers,
// stage tile t+2, steady wait vmcnt(4). 256 blocks (1/CU), XCD-swizzled.
// ---------------------------------------------------------------------------
__global__ __launch_bounds__(512, 2)
void gemm_energy(const unsigned short* __restrict__ q16,
                 float* __restrict__ part) {
    // XCD-aware swizzle: 256 = 8 * 32
    int p = blockIdx.x;
    int l = (p & 7) * 32 + (p >> 3);
    int tile = l & 3, ks = (l >> 2) & 3, b = l >> 4;
    int m0 = (tile >> 1) * 256, n0 = (tile & 1) * 256;
    int kbeg = ks * 1024;
    const int NT = 32;                       // 1024 / 32

    const char* Ab = (const char*)(q16 + (size_t)b * C_ * N_);
    const int rowB = N_ * 2;

    __shared__ unsigned short As[3][256 * 32];
    __shared__ unsigned short Bs[3][256 * 32];

    int t = threadIdx.x;
    int lane = t & 63, wave = t >> 6;
    int wm = (wave >> 2) * 128, wn = (wave & 3) * 64;
    int qd = lane >> 4, r = lane & 15;

    f32x4 acc[8][4] = {};

    stage_pair512(Ab, Ab, (char*)As[0], (char*)Bs[0], t, rowB, m0, n0, (kbeg +  0) * 2);
    stage_pair512(Ab, Ab, (char*)As[1], (char*)Bs[1], t, rowB, m0, n0, (kbeg + 32) * 2);

    for (int tt = 0; tt < NT; ++tt) {
        if (tt < NT - 1) asm volatile("s_waitcnt vmcnt(4) lgkmcnt(0)" ::: "memory");
        else             asm volatile("s_waitcnt vmcnt(0) lgkmcnt(0)" ::: "memory");
        __builtin_amdgcn_s_barrier();

        if (tt + 2 < NT) {
            int nb = tt + 2; while (nb >= 3) nb -= 3;
            stage_pair512(Ab, Ab, (char*)As[nb], (char*)Bs[nb], t, rowB,
                          m0, n0, (kbeg + (tt + 2) * 32) * 2);
        }

        int cb = tt; while (cb >= 3) cb -= 3;
        const unsigned short* as = As[cb];
        const unsigned short* bs = Bs[cb];
        bf16x8 af[8], bfr[4];
#pragma unroll
        for (int i = 0; i < 8; ++i)
            af[i] = *(const bf16x8*)&as[(wm + i * 16 + r) * 32 + qd * 8];
#pragma unroll
        for (int j = 0; j < 4; ++j)
            bfr[j] = *(const bf16x8*)&bs[(wn + j * 16 + r) * 32 + qd * 8];

        __builtin_amdgcn_s_setprio(1);
#pragma unroll
        for (int i = 0; i < 8; ++i)
#pragma unroll
            for (int j = 0; j < 4; ++j)
                acc[i][j] = __builtin_amdgcn_mfma_f32_16x16x32_bf16(af[i], bfr[j], acc[i][j], 0, 0, 0);
        __builtin_amdgcn_s_setprio(0);
    }

    float* Db = part + ((size_t)ks * B_ + b) * C_ * C_;
#pragma unroll
    for (int i = 0; i < 8; ++i)
#pragma unroll
        for (int j = 0; j < 4; ++j) {
            int row = m0 + wm + i * 16 + qd * 4;
            int col = n0 + wn + j * 16 + r;
#pragma unroll
            for (int rr = 0; rr < 4; ++rr)
                Db[(size_t)(row + rr) * C_ + col] = acc[i][j][rr];
        }
}

// ---------------------------------------------------------------------------
// Kernel 3: attention = softmax(-energy) row-wise, summing 4 split-K
// partials inline. One block per (b,c) row; output bf16.
// ---------------------------------------------------------------------------
__global__ __launch_bounds__(256)
void softmax_neg(const float* __restrict__ part, unsigned short* __restrict__ att) {
    size_t row = blockIdx.x;
    const size_t PS = (size_t)B_ * C_ * C_;
    const float* e = part + row * C_;
    int t = threadIdx.x;

    float x0 = e[t]       + e[PS + t]       + e[2 * PS + t]       + e[3 * PS + t];
    float x1 = e[t + 256] + e[PS + t + 256] + e[2 * PS + t + 256] + e[3 * PS + t + 256];
    float m = fminf(x0, x1);                 // min(e) == -max(-e)
#pragma unroll
    for (int off = 32; off > 0; off >>= 1) m = fminf(m, __shfl_down(m, off, 64));
    __shared__ float red[8];
    if ((t & 63) == 0) red[t >> 6] = m;
    __syncthreads();
    m = fminf(fminf(red[0], red[1]), fminf(red[2], red[3]));

    float p0 = __expf(m - x0), p1 = __expf(m - x1);
    float s = p0 + p1;
#pragma unroll
    for (int off = 32; off > 0; off >>= 1) s += __shfl_down(s, off, 64);
    if ((t & 63) == 0) red[4 + (t >> 6)] = s;
    __syncthreads();
    s = red[4] + red[5] + red[6] + red[7];
    float inv = 1.0f / s;

    att[row * C_ + t]       = f2bf(p0 * inv);
    att[row * C_ + t + 256] = f2bf(p1 * inv);
}

// ---------------------------------------------------------------------------
// Kernel 4: y[b] = gamma * (attention[b] . Q[b]) + x[b]
// 256x256 tiles, 8 waves, depth-2 counted-vmcnt loop, XCD swizzle.
// Halves staging traffic vs 128x128 (A,B panels re-read 2x fewer tiles).
// ---------------------------------------------------------------------------
__global__ __launch_bounds__(512, 2)
void gemm_bt_out(const unsigned short* __restrict__ att,
                 const unsigned short* __restrict__ qt16,
                 const float* __restrict__ x,
                 const float* __restrict__ gamma,
                 float* __restrict__ y) {
    const int K = 512;
    const int NT = K / 32;   // 16
    // XCD swizzle: 512 = 8 * 64
    int p = blockIdx.x;
    int l = (p & 7) * 64 + (p >> 3);
    int bx = l & 15, by = (l >> 4) & 1, b = l >> 5;

    const char* Ab = (const char*)(att  + (size_t)b * C_ * K);
    const char* Bb = (const char*)(qt16 + (size_t)b * N_ * K);
    int m0 = by * 256;    // c
    int n0 = bx * 256;    // n (spatial)

    __shared__ unsigned short As[3][256 * 32];
    __shared__ unsigned short Bs[3][256 * 32];

    int t = threadIdx.x;
    int lane = t & 63, wave = t >> 6;
    int wm = (wave >> 2) * 128, wn = (wave & 3) * 64;
    int qd = lane >> 4, r = lane & 15;

    f32x4 acc[8][4] = {};

    const int rowB = K * 2;
    stage_pair512(Ab, Bb, (char*)As[0], (char*)Bs[0], t, rowB, m0, n0, 0);
    stage_pair512(Ab, Bb, (char*)As[1], (char*)Bs[1], t, rowB, m0, n0, 64);

    for (int tt = 0; tt < NT; ++tt) {
        if (tt < NT - 1) asm volatile("s_waitcnt vmcnt(4) lgkmcnt(0)" ::: "memory");
        else             asm volatile("s_waitcnt vmcnt(0) lgkmcnt(0)" ::: "memory");
        __builtin_amdgcn_s_barrier();

        if (tt + 2 < NT) {
            int nb = tt + 2; while (nb >= 3) nb -= 3;
            stage_pair512(Ab, Bb, (char*)As[nb], (char*)Bs[nb], t, rowB,
                          m0, n0, (tt + 2) * 64);
        }

        int cb = tt; while (cb >= 3) cb -= 3;
        const unsigned short* as = As[cb];
        const unsigned short* bs = Bs[cb];
        bf16x8 af[8], bfr[4];
#pragma unroll
        for (int i = 0; i < 8; ++i)
            af[i] = *(const bf16x8*)&as[(wm + i * 16 + r) * 32 + qd * 8];
#pragma unroll
        for (int j = 0; j < 4; ++j)
            bfr[j] = *(const bf16x8*)&bs[(wn + j * 16 + r) * 32 + qd * 8];

        __builtin_amdgcn_s_setprio(1);
#pragma unroll
        for (int i = 0; i < 8; ++i)
#pragma unroll
            for (int j = 0; j < 4; ++j)
                acc[i][j] = __builtin_amdgcn_mfma_f32_16x16x32_bf16(af[i], bfr[j], acc[i][j], 0, 0, 0);
        __builtin_amdgcn_s_setprio(0);
    }

    float g = gamma[0];
    const float* xb = x + (size_t)b * C_ * N_;
    float*       yb = y + (size_t)b * C_ * N_;
#pragma unroll
    for (int i = 0; i < 8; ++i)
#pragma unroll
        for (int j = 0; j < 4; ++j) {
            int row = m0 + wm + i * 16 + qd * 4;
            int col = n0 + wn + j * 16 + r;
#pragma unroll
            for (int rr = 0; rr < 4; ++rr) {
                size_t idx = (size_t)(row + rr) * N_ + col;
                yb[idx] = g * acc[i][j][rr] + xb[idx];
            }
        }
}

// ---------------------------------------------------------------------------
// Workspace layout (bytes):
//   q16   @ 0          : 67,108,864
//   qt16  @ 67108864   : 67,108,864
//   att16 @ 134217728  :  8,388,608     -> ws use 142,606,336
// Energy partials (4 x 16 MB = 64 MB) live in d_out, which is scratch until
// gemm_bt_out writes y at the end of the stream.
// ---------------------------------------------------------------------------
extern "C" void kernel_launch(void* const* d_in, const int* in_sizes, int n_in,
                              void* d_out, int out_size, void* d_ws, size_t ws_size,
                              hipStream_t stream) {
    const float* x     = (const float*)d_in[0];
    const float* gamma = (const float*)d_in[1];
    float*       y     = (float*)d_out;

    char* ws = (char*)d_ws;
    unsigned short* q16   = (unsigned short*)(ws);
    unsigned short* qt16  = (unsigned short*)(ws + 67108864);
    unsigned short* att16 = (unsigned short*)(ws + 134217728);
    float*          part  = (float*)d_out;   // 4 x 16 MB scratch partials

    convert_transpose<<<dim3(N_ / 64, C_ / 64, B_), dim3(256), 0, stream>>>(x, q16, qt16);
    gemm_energy<<<dim3(256), dim3(512), 0, stream>>>(q16, part);
    softmax_neg<<<dim3(B_ * C_), dim3(256), 0, stream>>>(part, att16);
    gemm_bt_out<<<dim3(512), dim3(512), 0, stream>>>(att16, qt16, x, gamma, y);
}

// Round 5
// 388.758 us; speedup vs baseline: 1.0919x; 1.0049x over previous
//
#include <hip/hip_runtime.h>
#include <stdint.h>

#define B_ 16
#define C_ 512
#define N_ 4096

typedef float f32x4 __attribute__((ext_vector_type(4)));
typedef __bf16 bf16x8 __attribute__((ext_vector_type(8)));

// fp32 -> bf16 round-to-nearest-even (inputs are finite normals; no NaN path needed)
static __device__ __forceinline__ unsigned short f2bf(float f) {
    unsigned int u = __float_as_uint(f);
    u += 0x7fffu + ((u >> 16) & 1u);
    return (unsigned short)(u >> 16);
}

// async global->LDS, 16B per lane (global_load_lds_dwordx4)
static __device__ __forceinline__ void gload_lds16(const void* g, void* l) {
    __builtin_amdgcn_global_load_lds(
        (__attribute__((address_space(1))) unsigned int*)(g),
        (__attribute__((address_space(3))) unsigned int*)(l),
        16, 0, 0);
}

// ---------------------------------------------------------------------------
// Kernel 1: x (fp32, BxCxN) -> q16 (bf16, BxCxN) and qt16 (bf16, BxNxC)
// LDS 64x64 tile transpose, pitch 65 (conflict-free transpose reads).
// Both q16 (from regs) and qt16 (from LDS) written as 128-B segments.
// ---------------------------------------------------------------------------
__global__ __launch_bounds__(256)
void convert_transpose(const float* __restrict__ x,
                       unsigned short* __restrict__ q16,
                       unsigned short* __restrict__ qt16) {
    __shared__ unsigned short tile[64][65];   // pitch 65: transpose reads hit 32 banks
    int b  = blockIdx.z;
    int c0 = blockIdx.y * 64, n0 = blockIdx.x * 64;
    int tx = threadIdx.x & 15, ty = threadIdx.x >> 4;

    const float*    xb  = x    + ((size_t)b * C_ + c0) * N_ + n0;
    unsigned short* qb  = q16  + ((size_t)b * C_ + c0) * N_ + n0;
    unsigned short* qtb = qt16 + ((size_t)b * N_ + n0) * C_ + c0;

#pragma unroll
    for (int s = 0; s < 4; ++s) {
        int rr = s * 16 + ty;
        float4 v = *(const float4*)(xb + (size_t)rr * N_ + tx * 4);
        unsigned short h0 = f2bf(v.x), h1 = f2bf(v.y), h2 = f2bf(v.z), h3 = f2bf(v.w);
        tile[rr][tx * 4 + 0] = h0;
        tile[rr][tx * 4 + 1] = h1;
        tile[rr][tx * 4 + 2] = h2;
        tile[rr][tx * 4 + 3] = h3;
        ushort4 p; p.x = h0; p.y = h1; p.z = h2; p.w = h3;
        *(ushort4*)(qb + (size_t)rr * N_ + tx * 4) = p;
    }
    __syncthreads();
#pragma unroll
    for (int s = 0; s < 4; ++s) {
        int nr = s * 16 + ty;
        ushort4 p;
        p.x = tile[tx * 4 + 0][nr];
        p.y = tile[tx * 4 + 1][nr];
        p.z = tile[tx * 4 + 2][nr];
        p.w = tile[tx * 4 + 3][nr];
        *(ushort4*)(qtb + (size_t)nr * C_ + tx * 4) = p;
    }
}

// ---------------------------------------------------------------------------
// Shared GEMM structure: 128x128 tile, 4 waves, BK=32.
// LDS per K-tile: interleaved conflict-free layout, 128 rows x 8 slots x 16B.
//   slot s of row r holds logical chunk code = s ^ (r&7), code = isB*4 + qd:
//     isB=0 -> A[m0+r][k: qd*8..+7], isB=1 -> B[n0+r][k: qd*8..+7]  (bf16)
//   Read af[i]: byte (wm+i*16+r)*128 + ((qd^(r&7))<<4)  -> each quarter-wave
//   covers all 8 bank-groups exactly 2x => 2-way (free, m136).
// 2 buffers (32 KB), depth-2: stage(t+2) issued AFTER all reads of buffer
// (t&1) are certified done (lgkmcnt(0) + barrier), wait vmcnt(4) at iter top
// certifies stage(t) landed (stage(t+1)'s 4 loads may fly). Never drains.
// ---------------------------------------------------------------------------

// ---------------------------------------------------------------------------
// Kernel 2: energy partials, split-K x2.
//   e{0,1}[b] (f32 512x512) = Q[b][:, ks*2048:+2048] . (same)^T
// 512 blocks (2+/CU). Block mapping keeps one (b,ks) group per XCD.
// ---------------------------------------------------------------------------
__global__ __launch_bounds__(256, 3)
void gemm_energy(const unsigned short* __restrict__ q16,
                 float* __restrict__ e0, float* __restrict__ e1) {
    int bid = blockIdx.x;
    int g = bid & 31, tl = bid >> 5;          // xcd = bid%8 = g%8 -> per-(b,ks) grouping
    int b = g >> 1, ks = g & 1;
    int m0 = (tl >> 2) * 128, n0 = (tl & 3) * 128;
    const int NT = 64;                         // 2048 / 32
    const int rowB = N_ * 2;
    const char* Ab = (const char*)(q16 + (size_t)b * C_ * N_);
    int kbegByte = ks * 2048 * 2;

    __shared__ char lds[2][16384];

    int t = threadIdx.x;
    int lane = t & 63, wave = t >> 6;
    int wm = (wave >> 1) * 64, wn = (wave & 1) * 64;
    int qd = lane >> 4, r = lane & 15;

    // stage sources (loop-invariant) + LDS dests
    const char* src[4];
#pragma unroll
    for (int i = 0; i < 4; ++i) {
        int v = i * 256 + t;
        int row = v >> 3, slot = v & 7, code = slot ^ (row & 7);
        int isB = code >> 2, col = (code & 3) * 16;
        src[i] = Ab + (size_t)((isB ? n0 : m0) + row) * rowB + kbegByte + col;
    }
    int aoff = (wm + r) * 128 + ((qd ^ (r & 7)) << 4);
    int boff = (wn + r) * 128 + (((4 | qd) ^ (r & 7)) << 4);

    f32x4 acc[4][4] = {};

    // prologue: tiles 0,1
#pragma unroll
    for (int i = 0; i < 4; ++i) gload_lds16(src[i],      &lds[0][(i * 256 + t) * 16]);
#pragma unroll
    for (int i = 0; i < 4; ++i) gload_lds16(src[i] + 64, &lds[1][(i * 256 + t) * 16]);

    for (int tt = 0; tt < NT; ++tt) {
        if (tt < NT - 1) asm volatile("s_waitcnt vmcnt(4)" ::: "memory");
        else             asm volatile("s_waitcnt vmcnt(0)" ::: "memory");
        __builtin_amdgcn_s_barrier();

        const char* base = lds[tt & 1];
        bf16x8 af[4], bfr[4];
#pragma unroll
        for (int i = 0; i < 4; ++i) af[i]  = *(const bf16x8*)(base + aoff + i * 2048);
#pragma unroll
        for (int j = 0; j < 4; ++j) bfr[j] = *(const bf16x8*)(base + boff + j * 2048);
        asm volatile("s_waitcnt lgkmcnt(0)" ::: "memory");
        __builtin_amdgcn_s_barrier();

        if (tt + 2 < NT) {
            int kB = (tt + 2) * 64;
            char* d = lds[tt & 1];
#pragma unroll
            for (int i = 0; i < 4; ++i) gload_lds16(src[i] + kB, d + (i * 256 + t) * 16);
        }

        __builtin_amdgcn_s_setprio(1);
#pragma unroll
        for (int i = 0; i < 4; ++i)
#pragma unroll
            for (int j = 0; j < 4; ++j)
                acc[i][j] = __builtin_amdgcn_mfma_f32_16x16x32_bf16(af[i], bfr[j], acc[i][j], 0, 0, 0);
        __builtin_amdgcn_s_setprio(0);
    }

    float* Db = (ks ? e1 : e0) + (size_t)b * C_ * C_;
#pragma unroll
    for (int i = 0; i < 4; ++i)
#pragma unroll
        for (int j = 0; j < 4; ++j) {
            int row = m0 + wm + i * 16 + qd * 4;
            int col = n0 + wn + j * 16 + r;
#pragma unroll
            for (int rr = 0; rr < 4; ++rr)
                Db[(size_t)(row + rr) * C_ + col] = acc[i][j][rr];
        }
}

// ---------------------------------------------------------------------------
// Kernel 3: attention = softmax(-energy) row-wise, summing the two split-K
// partials inline. One block per (b,c) row; output bf16.
// ---------------------------------------------------------------------------
__global__ __launch_bounds__(256)
void softmax_neg(const float* __restrict__ e0, const float* __restrict__ e1,
                 unsigned short* __restrict__ att) {
    size_t row = blockIdx.x;
    const float* a = e0 + row * C_;
    const float* c = e1 + row * C_;
    int t = threadIdx.x;

    float x0 = a[t] + c[t], x1 = a[t + 256] + c[t + 256];
    float m = fminf(x0, x1);                 // min(e) == -max(-e)
#pragma unroll
    for (int off = 32; off > 0; off >>= 1) m = fminf(m, __shfl_down(m, off, 64));
    __shared__ float red[8];
    if ((t & 63) == 0) red[t >> 6] = m;
    __syncthreads();
    m = fminf(fminf(red[0], red[1]), fminf(red[2], red[3]));

    float p0 = __expf(m - x0), p1 = __expf(m - x1);
    float s = p0 + p1;
#pragma unroll
    for (int off = 32; off > 0; off >>= 1) s += __shfl_down(s, off, 64);
    if ((t & 63) == 0) red[4 + (t >> 6)] = s;
    __syncthreads();
    s = red[4] + red[5] + red[6] + red[7];
    float inv = 1.0f / s;

    att[row * C_ + t]       = f2bf(p0 * inv);
    att[row * C_ + t + 256] = f2bf(p1 * inv);
}

// ---------------------------------------------------------------------------
// Kernel 4: y[b] = gamma * (attention[b] . Q[b]) + x[b]
// 2048 blocks, 3-4/CU: overlapping blocks hide epilogue bursts + drains.
// Block mapping: one (b, n-chunk) qt16 panel (2 MB) per XCD.
// ---------------------------------------------------------------------------
__global__ __launch_bounds__(256, 3)
void gemm_bt_out(const unsigned short* __restrict__ att,
                 const unsigned short* __restrict__ qt16,
                 const float* __restrict__ x,
                 const float* __restrict__ gamma,
                 float* __restrict__ y) {
    const int K = 512;
    const int NT = K / 32;   // 16
    int bid = blockIdx.x;
    int g = bid & 127, tl = bid >> 7;          // xcd = g%8 = nchunk
    int b = g >> 3, nch = g & 7;
    int m0 = (tl >> 2) * 128;
    int n0 = (nch * 4 + (tl & 3)) * 128;
    const int rowB = K * 2;
    const char* Ab = (const char*)(att  + (size_t)b * C_ * K);
    const char* Bb = (const char*)(qt16 + (size_t)b * N_ * K);

    __shared__ char lds[2][16384];

    int t = threadIdx.x;
    int lane = t & 63, wave = t >> 6;
    int wm = (wave >> 1) * 64, wn = (wave & 1) * 64;
    int qd = lane >> 4, r = lane & 15;

    const char* src[4];
#pragma unroll
    for (int i = 0; i < 4; ++i) {
        int v = i * 256 + t;
        int row = v >> 3, slot = v & 7, code = slot ^ (row & 7);
        int isB = code >> 2, col = (code & 3) * 16;
        src[i] = (isB ? Bb + (size_t)(n0 + row) * rowB
                      : Ab + (size_t)(m0 + row) * rowB) + col;
    }
    int aoff = (wm + r) * 128 + ((qd ^ (r & 7)) << 4);
    int boff = (wn + r) * 128 + (((4 | qd) ^ (r & 7)) << 4);

    f32x4 acc[4][4] = {};

#pragma unroll
    for (int i = 0; i < 4; ++i) gload_lds16(src[i],      &lds[0][(i * 256 + t) * 16]);
#pragma unroll
    for (int i = 0; i < 4; ++i) gload_lds16(src[i] + 64, &lds[1][(i * 256 + t) * 16]);

    for (int tt = 0; tt < NT; ++tt) {
        if (tt < NT - 1) asm volatile("s_waitcnt vmcnt(4)" ::: "memory");
        else             asm volatile("s_waitcnt vmcnt(0)" ::: "memory");
        __builtin_amdgcn_s_barrier();

        const char* base = lds[tt & 1];
        bf16x8 af[4], bfr[4];
#pragma unroll
        for (int i = 0; i < 4; ++i) af[i]  = *(const bf16x8*)(base + aoff + i * 2048);
#pragma unroll
        for (int j = 0; j < 4; ++j) bfr[j] = *(const bf16x8*)(base + boff + j * 2048);
        asm volatile("s_waitcnt lgkmcnt(0)" ::: "memory");
        __builtin_amdgcn_s_barrier();

        if (tt + 2 < NT) {
            int kB = (tt + 2) * 64;
            char* d = lds[tt & 1];
#pragma unroll
            for (int i = 0; i < 4; ++i) gload_lds16(src[i] + kB, d + (i * 256 + t) * 16);
        }

        __builtin_amdgcn_s_setprio(1);
#pragma unroll
        for (int i = 0; i < 4; ++i)
#pragma unroll
            for (int j = 0; j < 4; ++j)
                acc[i][j] = __builtin_amdgcn_mfma_f32_16x16x32_bf16(af[i], bfr[j], acc[i][j], 0, 0, 0);
        __builtin_amdgcn_s_setprio(0);
    }

    float g_ = gamma[0];
    const float* xb = x + (size_t)b * C_ * N_;
    float*       yb = y + (size_t)b * C_ * N_;
#pragma unroll
    for (int i = 0; i < 4; ++i)
#pragma unroll
        for (int j = 0; j < 4; ++j) {
            int row = m0 + wm + i * 16 + qd * 4;
            int col = n0 + wn + j * 16 + r;
#pragma unroll
            for (int rr = 0; rr < 4; ++rr) {
                size_t idx = (size_t)(row + rr) * N_ + col;
                yb[idx] = g_ * acc[i][j][rr] + xb[idx];
            }
        }
}

// ---------------------------------------------------------------------------
// Workspace layout (bytes):
//   q16   @ 0          : 67,108,864
//   qt16  @ 67108864   : 67,108,864
//   att16 @ 134217728  :  8,388,608
//   e0    @ 142606336  : 16,777,216      -> total 159,383,552
//   e1 = d_out (scratch; fully overwritten by gemm_bt_out afterwards)
// ---------------------------------------------------------------------------
extern "C" void kernel_launch(void* const* d_in, const int* in_sizes, int n_in,
                              void* d_out, int out_size, void* d_ws, size_t ws_size,
                              hipStream_t stream) {
    const float* x     = (const float*)d_in[0];
    const float* gamma = (const float*)d_in[1];
    float*       y     = (float*)d_out;

    char* ws = (char*)d_ws;
    unsigned short* q16   = (unsigned short*)(ws);
    unsigned short* qt16  = (unsigned short*)(ws + 67108864);
    unsigned short* att16 = (unsigned short*)(ws + 134217728);
    float*          e0    = (float*)(ws + 142606336);
    float*          e1    = (float*)d_out;   // scratch until gemm_bt_out runs

    convert_transpose<<<dim3(N_ / 64, C_ / 64, B_), dim3(256), 0, stream>>>(x, q16, qt16);
    gemm_energy<<<dim3(512), dim3(256), 0, stream>>>(q16, e0, e1);
    softmax_neg<<<dim3(B_ * C_), dim3(256), 0, stream>>>(e0, e1, att16);
    gemm_bt_out<<<dim3(2048), dim3(256), 0, stream>>>(att16, qt16, x, gamma, y);
}

// Round 7
// 371.281 us; speedup vs baseline: 1.1433x; 1.0471x over previous
//
#include <hip/hip_runtime.h>
#include <stdint.h>

#define B_ 16
#define C_ 512
#define N_ 4096

typedef float f32x4 __attribute__((ext_vector_type(4)));
typedef __bf16 bf16x8 __attribute__((ext_vector_type(8)));

// fp32 -> bf16 round-to-nearest-even (inputs are finite normals; no NaN path needed)
static __device__ __forceinline__ unsigned short f2bf(float f) {
    unsigned int u = __float_as_uint(f);
    u += 0x7fffu + ((u >> 16) & 1u);
    return (unsigned short)(u >> 16);
}

// async global->LDS, 16B per lane (global_load_lds_dwordx4)
static __device__ __forceinline__ void gload_lds16(const void* g, void* l) {
    __builtin_amdgcn_global_load_lds(
        (__attribute__((address_space(1))) unsigned int*)(g),
        (__attribute__((address_space(3))) unsigned int*)(l),
        16, 0, 0);
}

// ---------------------------------------------------------------------------
// Kernel 1: x (fp32, BxCxN) -> q16 (bf16, BxCxN) and qt16 (bf16, BxNxC)
// LDS 64x64 tile transpose, pitch 65 (conflict-free transpose reads).
// ---------------------------------------------------------------------------
__global__ __launch_bounds__(256)
void convert_transpose(const float* __restrict__ x,
                       unsigned short* __restrict__ q16,
                       unsigned short* __restrict__ qt16) {
    __shared__ unsigned short tile[64][65];   // pitch 65: transpose reads hit 32 banks
    int b  = blockIdx.z;
    int c0 = blockIdx.y * 64, n0 = blockIdx.x * 64;
    int tx = threadIdx.x & 15, ty = threadIdx.x >> 4;

    const float*    xb  = x    + ((size_t)b * C_ + c0) * N_ + n0;
    unsigned short* qb  = q16  + ((size_t)b * C_ + c0) * N_ + n0;
    unsigned short* qtb = qt16 + ((size_t)b * N_ + n0) * C_ + c0;

#pragma unroll
    for (int s = 0; s < 4; ++s) {
        int rr = s * 16 + ty;
        float4 v = *(const float4*)(xb + (size_t)rr * N_ + tx * 4);
        unsigned short h0 = f2bf(v.x), h1 = f2bf(v.y), h2 = f2bf(v.z), h3 = f2bf(v.w);
        tile[rr][tx * 4 + 0] = h0;
        tile[rr][tx * 4 + 1] = h1;
        tile[rr][tx * 4 + 2] = h2;
        tile[rr][tx * 4 + 3] = h3;
        ushort4 p; p.x = h0; p.y = h1; p.z = h2; p.w = h3;
        *(ushort4*)(qb + (size_t)rr * N_ + tx * 4) = p;
    }
    __syncthreads();
#pragma unroll
    for (int s = 0; s < 4; ++s) {
        int nr = s * 16 + ty;
        ushort4 p;
        p.x = tile[tx * 4 + 0][nr];
        p.y = tile[tx * 4 + 1][nr];
        p.z = tile[tx * 4 + 2][nr];
        p.w = tile[tx * 4 + 3][nr];
        *(ushort4*)(qtb + (size_t)nr * C_ + tx * 4) = p;
    }
}

// ---------------------------------------------------------------------------
// Shared GEMM structure (r5-proven): 128x128 tile, 4 waves, BK=32.
// LDS per K-tile: interleaved XOR layout, 128 rows x 8 slots x 16B;
// slot s of row r holds chunk code = s ^ (r&7), code = isB*4 + qd.
// Reads are 2-way bank aliased (free, m136); measured 0 conflicts (r5).
// 2 buffers (32 KB), depth-2, counted vmcnt(4), never drains mid-loop.
// ---------------------------------------------------------------------------

// ---------------------------------------------------------------------------
// Kernel 2: energy partials, split-K x2.
//   e{0,1}[b] (f32 512x512) = Q[b][:, ks*2048:+2048] . (same)^T
// 512 blocks. Mapping (r6 fix): XCD = bid%8 (round-robin), j = bid>>3 is the
// XCD-local time index; tile tl = j&15 FAST, (b,ks) combo = xcd*4 + (j>>4)
// SLOW -> 16 temporally-consecutive blocks share one 2 MB Q k-slice (L2-fits).
// ---------------------------------------------------------------------------
__global__ __launch_bounds__(256, 3)
void gemm_energy(const unsigned short* __restrict__ q16,
                 float* __restrict__ e0, float* __restrict__ e1) {
    int bid = blockIdx.x;
    int xcd = bid & 7;
    int j   = bid >> 3;                  // 0..63
    int tl  = j & 15;                    // fast: tile within panel
    int combo = xcd * 4 + (j >> 4);      // slow: 32 (b,ks) combos
    int b = combo >> 1, ks = combo & 1;
    int m0 = (tl >> 2) * 128, n0 = (tl & 3) * 128;
    const int NT = 64;                   // 2048 / 32
    const int rowB = N_ * 2;
    const char* Ab = (const char*)(q16 + (size_t)b * C_ * N_);
    int kbegByte = ks * 2048 * 2;

    __shared__ char lds[2][16384];

    int t = threadIdx.x;
    int lane = t & 63, wave = t >> 6;
    int wm = (wave >> 1) * 64, wn = (wave & 1) * 64;
    int qd = lane >> 4, r = lane & 15;

    // stage sources (loop-invariant) + LDS dests
    const char* src[4];
#pragma unroll
    for (int i = 0; i < 4; ++i) {
        int v = i * 256 + t;
        int row = v >> 3, slot = v & 7, code = slot ^ (row & 7);
        int isB = code >> 2, col = (code & 3) * 16;
        src[i] = Ab + (size_t)((isB ? n0 : m0) + row) * rowB + kbegByte + col;
    }
    int aoff = (wm + r) * 128 + ((qd ^ (r & 7)) << 4);
    int boff = (wn + r) * 128 + (((4 | qd) ^ (r & 7)) << 4);

    f32x4 acc[4][4] = {};

    // prologue: tiles 0,1
#pragma unroll
    for (int i = 0; i < 4; ++i) gload_lds16(src[i],      &lds[0][(i * 256 + t) * 16]);
#pragma unroll
    for (int i = 0; i < 4; ++i) gload_lds16(src[i] + 64, &lds[1][(i * 256 + t) * 16]);

    for (int tt = 0; tt < NT; ++tt) {
        if (tt < NT - 1) asm volatile("s_waitcnt vmcnt(4)" ::: "memory");
        else             asm volatile("s_waitcnt vmcnt(0)" ::: "memory");
        __builtin_amdgcn_s_barrier();

        const char* base = lds[tt & 1];
        bf16x8 af[4], bfr[4];
#pragma unroll
        for (int i = 0; i < 4; ++i) af[i]  = *(const bf16x8*)(base + aoff + i * 2048);
#pragma unroll
        for (int j2 = 0; j2 < 4; ++j2) bfr[j2] = *(const bf16x8*)(base + boff + j2 * 2048);
        asm volatile("s_waitcnt lgkmcnt(0)" ::: "memory");
        __builtin_amdgcn_s_barrier();

        if (tt + 2 < NT) {
            int kB = (tt + 2) * 64;
            char* d = lds[tt & 1];
#pragma unroll
            for (int i = 0; i < 4; ++i) gload_lds16(src[i] + kB, d + (i * 256 + t) * 16);
        }

        __builtin_amdgcn_s_setprio(1);
#pragma unroll
        for (int i = 0; i < 4; ++i)
#pragma unroll
            for (int j2 = 0; j2 < 4; ++j2)
                acc[i][j2] = __builtin_amdgcn_mfma_f32_16x16x32_bf16(af[i], bfr[j2], acc[i][j2], 0, 0, 0);
        __builtin_amdgcn_s_setprio(0);
    }

    float* Db = (ks ? e1 : e0) + (size_t)b * C_ * C_;
#pragma unroll
    for (int i = 0; i < 4; ++i)
#pragma unroll
        for (int j2 = 0; j2 < 4; ++j2) {
            int row = m0 + wm + i * 16 + qd * 4;
            int col = n0 + wn + j2 * 16 + r;
#pragma unroll
            for (int rr = 0; rr < 4; ++rr)
                Db[(size_t)(row + rr) * C_ + col] = acc[i][j2][rr];
        }
}

// ---------------------------------------------------------------------------
// Kernel 3: attention = softmax(-energy) row-wise, summing the two split-K
// partials inline. One block per (b,c) row; output bf16.
// ---------------------------------------------------------------------------
__global__ __launch_bounds__(256)
void softmax_neg(const float* __restrict__ e0, const float* __restrict__ e1,
                 unsigned short* __restrict__ att) {
    size_t row = blockIdx.x;
    const float* a = e0 + row * C_;
    const float* c = e1 + row * C_;
    int t = threadIdx.x;

    float x0 = a[t] + c[t], x1 = a[t + 256] + c[t + 256];
    float m = fminf(x0, x1);                 // min(e) == -max(-e)
#pragma unroll
    for (int off = 32; off > 0; off >>= 1) m = fminf(m, __shfl_down(m, off, 64));
    __shared__ float red[8];
    if ((t & 63) == 0) red[t >> 6] = m;
    __syncthreads();
    m = fminf(fminf(red[0], red[1]), fminf(red[2], red[3]));

    float p0 = __expf(m - x0), p1 = __expf(m - x1);
    float s = p0 + p1;
#pragma unroll
    for (int off = 32; off > 0; off >>= 1) s += __shfl_down(s, off, 64);
    if ((t & 63) == 0) red[4 + (t >> 6)] = s;
    __syncthreads();
    s = red[4] + red[5] + red[6] + red[7];
    float inv = 1.0f / s;

    att[row * C_ + t]       = f2bf(p0 * inv);
    att[row * C_ + t + 256] = f2bf(p1 * inv);
}

// ---------------------------------------------------------------------------
// Kernel 4: y[b] = gamma * (attention[b] . Q[b]) + x[b]
// 2048 blocks, 3 blocks/CU. Mapping (r6 fix): XCD = bid%8, j = bid>>3;
// tile tl = j&15 FAST within one (b, nch=xcd) panel, b = j>>4 SLOW.
// 16 temporally-consecutive blocks per XCD share one 512 KB qt-panel + att.
// ---------------------------------------------------------------------------
__global__ __launch_bounds__(256, 3)
void gemm_bt_out(const unsigned short* __restrict__ att,
                 const unsigned short* __restrict__ qt16,
                 const float* __restrict__ x,
                 const float* __restrict__ gamma,
                 float* __restrict__ y) {
    const int K = 512;
    const int NT = K / 32;   // 16
    int bid = blockIdx.x;
    int xcd = bid & 7;
    int j   = bid >> 3;                  // 0..255
    int tl  = j & 15;                    // fast: tile within panel
    int b   = j >> 4;                    // slow: batch
    int m0 = (tl >> 2) * 128;
    int n0 = (xcd * 4 + (tl & 3)) * 128;
    const int rowB = K * 2;
    const char* Ab = (const char*)(att  + (size_t)b * C_ * K);
    const char* Bb = (const char*)(qt16 + (size_t)b * N_ * K);

    __shared__ char lds[2][16384];

    int t = threadIdx.x;
    int lane = t & 63, wave = t >> 6;
    int wm = (wave >> 1) * 64, wn = (wave & 1) * 64;
    int qd = lane >> 4, r = lane & 15;

    const char* src[4];
#pragma unroll
    for (int i = 0; i < 4; ++i) {
        int v = i * 256 + t;
        int row = v >> 3, slot = v & 7, code = slot ^ (row & 7);
        int isB = code >> 2, col = (code & 3) * 16;
        src[i] = (isB ? Bb + (size_t)(n0 + row) * rowB
                      : Ab + (size_t)(m0 + row) * rowB) + col;
    }
    int aoff = (wm + r) * 128 + ((qd ^ (r & 7)) << 4);
    int boff = (wn + r) * 128 + (((4 | qd) ^ (r & 7)) << 4);

    f32x4 acc[4][4] = {};

#pragma unroll
    for (int i = 0; i < 4; ++i) gload_lds16(src[i],      &lds[0][(i * 256 + t) * 16]);
#pragma unroll
    for (int i = 0; i < 4; ++i) gload_lds16(src[i] + 64, &lds[1][(i * 256 + t) * 16]);

    for (int tt = 0; tt < NT; ++tt) {
        if (tt < NT - 1) asm volatile("s_waitcnt vmcnt(4)" ::: "memory");
        else             asm volatile("s_waitcnt vmcnt(0)" ::: "memory");
        __builtin_amdgcn_s_barrier();

        const char* base = lds[tt & 1];
        bf16x8 af[4], bfr[4];
#pragma unroll
        for (int i = 0; i < 4; ++i) af[i]  = *(const bf16x8*)(base + aoff + i * 2048);
#pragma unroll
        for (int j2 = 0; j2 < 4; ++j2) bfr[j2] = *(const bf16x8*)(base + boff + j2 * 2048);
        asm volatile("s_waitcnt lgkmcnt(0)" ::: "memory");
        __builtin_amdgcn_s_barrier();

        if (tt + 2 < NT) {
            int kB = (tt + 2) * 64;
            char* d = lds[tt & 1];
#pragma unroll
            for (int i = 0; i < 4; ++i) gload_lds16(src[i] + kB, d + (i * 256 + t) * 16);
        }

        __builtin_amdgcn_s_setprio(1);
#pragma unroll
        for (int i = 0; i < 4; ++i)
#pragma unroll
            for (int j2 = 0; j2 < 4; ++j2)
                acc[i][j2] = __builtin_amdgcn_mfma_f32_16x16x32_bf16(af[i], bfr[j2], acc[i][j2], 0, 0, 0);
        __builtin_amdgcn_s_setprio(0);
    }

    float g_ = gamma[0];
    const float* xb = x + (size_t)b * C_ * N_;
    float*       yb = y + (size_t)b * C_ * N_;
#pragma unroll
    for (int i = 0; i < 4; ++i)
#pragma unroll
        for (int j2 = 0; j2 < 4; ++j2) {
            int row = m0 + wm + i * 16 + qd * 4;
            int col = n0 + wn + j2 * 16 + r;
#pragma unroll
            for (int rr = 0; rr < 4; ++rr) {
                size_t idx = (size_t)(row + rr) * N_ + col;
                yb[idx] = g_ * acc[i][j2][rr] + xb[idx];
            }
        }
}

// ---------------------------------------------------------------------------
// Workspace layout (bytes):
//   q16   @ 0          : 67,108,864
//   qt16  @ 67108864   : 67,108,864
//   att16 @ 134217728  :  8,388,608
//   e0    @ 142606336  : 16,777,216      -> total 159,383,552
//   e1 = d_out (scratch; fully overwritten by gemm_bt_out afterwards)
// ---------------------------------------------------------------------------
extern "C" void kernel_launch(void* const* d_in, const int* in_sizes, int n_in,
                              void* d_out, int out_size, void* d_ws, size_t ws_size,
                              hipStream_t stream) {
    const float* x     = (const float*)d_in[0];
    const float* gamma = (const float*)d_in[1];
    float*       y     = (float*)d_out;

    char* ws = (char*)d_ws;
    unsigned short* q16   = (unsigned short*)(ws);
    unsigned short* qt16  = (unsigned short*)(ws + 67108864);
    unsigned short* att16 = (unsigned short*)(ws + 134217728);
    float*          e0    = (float*)(ws + 142606336);
    float*          e1    = (float*)d_out;   // scratch until gemm_bt_out runs

    convert_transpose<<<dim3(N_ / 64, C_ / 64, B_), dim3(256), 0, stream>>>(x, q16, qt16);
    gemm_energy<<<dim3(512), dim3(256), 0, stream>>>(q16, e0, e1);
    softmax_neg<<<dim3(B_ * C_), dim3(256), 0, stream>>>(e0, e1, att16);
    gemm_bt_out<<<dim3(2048), dim3(256), 0, stream>>>(att16, qt16, x, gamma, y);
}